// Round 8
// baseline (8153.360 us; speedup 1.0000x reference)
//
#include <hip/hip_runtime.h>

// Problem constants
#define BATCH 256
#define TT    64
#define HH    256
#define DD    8

// Tiling: 2 stacks * 128 batch-blocks of BW=2 -> 256 WGs (1/CU), 512 thr (8 waves)
#define BW    2
#define NTHR  512
#define NBLK  (2 * (BATCH / BW))

typedef __attribute__((ext_vector_type(8))) short bfrag;   // 8 bf16 (MFMA A/B operand)
typedef __attribute__((ext_vector_type(4))) float f4;      // MFMA C/D

#define SWZ(g) ((((g) & 31) << 3) | ((g) >> 5))

__device__ __forceinline__ float rcpf(float x) { return __builtin_amdgcn_rcpf(x); }
__device__ __forceinline__ float sigf(float x) { return rcpf(1.0f + __expf(-x)); }
__device__ __forceinline__ float tanh_fast(float x) {
  const float e = __expf(-2.0f * x);
  return __builtin_fmaf(2.0f, rcpf(1.0f + e), -1.0f);
}
__device__ __forceinline__ unsigned short f2bf(float f) {
  union { float f; unsigned int u; } v; v.f = f;
  return (unsigned short)((v.u + 0x7fffu + ((v.u >> 16) & 1u)) >> 16);
}
__device__ __forceinline__ float bf2f(unsigned short u) {
  union { unsigned int u; float f; } v; v.u = ((unsigned int)u) << 16; return v.f;
}
// fp8 e4m3 via HW cvt (round-trip self-consistent; OCP on gfx950)
__device__ __forceinline__ unsigned char f2fp8(float x) {
  return (unsigned char)(__builtin_amdgcn_cvt_pk_fp8_f32(x, 0.0f, 0, false) & 0xff);
}
__device__ __forceinline__ float fp8byte2f(unsigned int w, int byteshift) {
  return __builtin_amdgcn_cvt_f32_fp8(w >> byteshift, 0);
}
__device__ __forceinline__ bfrag zero_frag() {
  bfrag r;
#pragma unroll
  for (int x = 0; x < 8; x++) r[x] = 0;
  return r;
}
__device__ __forceinline__ f4 mfma16(bfrag a, bfrag b, f4 c) {
  return __builtin_amdgcn_mfma_f32_16x16x32_bf16(a, b, c, 0, 0, 0);
}

// ---------- weight fragment layout (UNCHANGED from rounds 4-7) ----------
#define W1_ELEMS  196608
#define STACK_W   (3 * W1_ELEMS)
#define B3_OFF    (2 * STACK_W)
#define B4_OFF    (B3_OFF + 131072)
#define WF_TOTAL  (B4_OFF + 131072)

__global__ __launch_bounds__(256) void prep_weights(
    const float* __restrict__ g1_Whh0, const float* __restrict__ g1_Wih1, const float* __restrict__ g1_Whh1,
    const float* __restrict__ g2_Whh0, const float* __restrict__ g2_Wih1, const float* __restrict__ g2_Whh1,
    const float* __restrict__ attn_W, const float* __restrict__ fc_W,
    unsigned short* __restrict__ wf) {
  const int id = blockIdx.x * 256 + threadIdx.x;
  if (id >= WF_TOTAL) return;
  float src;
  if (id < 2 * STACK_W) {
    const int s = id / STACK_W, r = id % STACK_W;
    const int mm = r / W1_ELEMS, e = r % W1_ELEMS;
    const int j = e & 7, lane = (e >> 3) & 63, c = (e >> 9) & 7, t = e >> 12;
    const int nt = t / 3, g = t % 3;
    const int n = nt * 16 + (lane & 15);
    const int k = c * 32 + ((lane >> 4) << 3) + j;
    const float* W = (mm == 0) ? (s ? g2_Whh0 : g1_Whh0)
                   : (mm == 1) ? (s ? g2_Wih1 : g1_Wih1)
                               : (s ? g2_Whh1 : g1_Whh1);
    src = W[(g * 256 + n) * 256 + k];
  } else if (id < B4_OFF) {
    const int e = id - B3_OFF;
    const int j = e & 7, lane = (e >> 3) & 63, c = (e >> 9) & 7, t = e >> 12;
    const int n = t * 16 + (lane & 15);
    const int k = c * 32 + ((lane >> 4) << 3) + j;
    src = (n < 256) ? attn_W[n * 512 + k] : attn_W[(n - 256) * 512 + 256 + k];
  } else {
    const int e = id - B4_OFF;
    const int j = e & 7, lane = (e >> 3) & 63, c = (e >> 9) & 15, t = e >> 13;
    const int n = t * 16 + (lane & 15);
    const int k = c * 32 + ((lane >> 4) << 3) + j;
    src = fc_W[n * 512 + k];
  }
  wf[id] = f2bf(src);
}

__global__ __launch_bounds__(NTHR, 2) void gru_attn(
    const float* __restrict__ received,
    const float* __restrict__ g1_Wih0, const float* __restrict__ g1_bih0, const float* __restrict__ g1_bhh0,
    const float* __restrict__ g1_bih1, const float* __restrict__ g1_bhh1,
    const float* __restrict__ g2_Wih0, const float* __restrict__ g2_bih0, const float* __restrict__ g2_bhh0,
    const float* __restrict__ g2_bih1, const float* __restrict__ g2_bhh1,
    const float* __restrict__ fc_b, const float* __restrict__ v_W, const float* __restrict__ out_W,
    const unsigned short* __restrict__ wf,
    unsigned int* __restrict__ bar, float* __restrict__ ws_p) {
  const int tid  = threadIdx.x;
  const int lane = tid & 63, wave = tid >> 6;   // 8 waves
  const int col  = lane & 15, q = lane >> 4;
  const int s    = blockIdx.x & 1;              // stack parity
  const int b0   = (blockIdx.x >> 1) * BW;

  const float* Wih0 = s ? g2_Wih0 : g1_Wih0;
  const float* bih0 = s ? g2_bih0 : g1_bih0;
  const float* bhh0 = s ? g2_bhh0 : g1_bhh0;
  const float* bih1 = s ? g2_bih1 : g1_bih1;
  const float* bhh1 = s ? g2_bhh1 : g1_bhh1;

  const bfrag* W1  = (const bfrag*)(wf + (size_t)s * STACK_W);
  const bfrag* W2I = W1 + W1_ELEMS / 8;
  const bfrag* W2H = W2I + W1_ELEMS / 8;
  const bfrag* B3  = (const bfrag*)(wf + B3_OFF);
  const bfrag* B4  = (const bfrag*)(wf + B4_OFF);

  float* pp = ws_p + (size_t)s * BATCH * TT;

  // Per-lane persistent constants, unit nm = (wave + 8*r2)*16 + col
  float wxr0v[2], wxr1v[2], wxz0v[2], wxz1v[2], wxn0v[2], wxn1v[2];
  float br0v[2], bz0v[2], bni0v[2], bnh0v[2];
  float br1v[2], bz1v[2], bni1v[2], bnh1v[2];
  float fcbv[2], owvv[2];
#pragma unroll
  for (int r2 = 0; r2 < 2; r2++) {
    const int nm = (wave + 8 * r2) * 16 + col;
    wxr0v[r2] = Wih0[nm * 2];         wxr1v[r2] = Wih0[nm * 2 + 1];
    wxz0v[r2] = Wih0[(256 + nm) * 2]; wxz1v[r2] = Wih0[(256 + nm) * 2 + 1];
    wxn0v[r2] = Wih0[(512 + nm) * 2]; wxn1v[r2] = Wih0[(512 + nm) * 2 + 1];
    br0v[r2]  = bih0[nm] + bhh0[nm];
    bz0v[r2]  = bih0[256 + nm] + bhh0[256 + nm];
    bni0v[r2] = bih0[512 + nm]; bnh0v[r2] = bhh0[512 + nm];
    br1v[r2]  = bih1[nm] + bhh1[nm];
    bz1v[r2]  = bih1[256 + nm] + bhh1[256 + nm];
    bni1v[r2] = bih1[512 + nm]; bnh1v[r2] = bhh1[512 + nm];
    fcbv[r2]  = fc_b[nm];
    owvv[r2]  = out_W[s * HH + nm];
  }

  // ---- LDS (~153 KB, 1 WG/CU). All history on-chip.
  __shared__ unsigned char  bufL[256 * 264];                            // hn hist fp8 [(j*2+l)*2+b][h]
  __shared__ unsigned char  ehL [256 * 272];                            // eh hist fp8 [(j*2+l)*2+b][g]
  __shared__ float          hf[4 * 260] __attribute__((aligned(16)));   // carry fp32
  __shared__ unsigned short hb[4 * 264] __attribute__((aligned(16)));   // carry bf16 (MFMA A)
  __shared__ unsigned short hnb[4 * 264] __attribute__((aligned(16)));  // fresh hidden bf16 [l*2+b]
  __shared__ float          es_s[4 * 264] __attribute__((aligned(16))); // s-projection [b*2+l][SWZ(g)]
  __shared__ unsigned short cacb[4 * 264] __attribute__((aligned(16))); // context bf16 [o*2+b]
  __shared__ float          lp[TT * 2 * 2 * 2];                         // exp(logit) [j][b][l][o]
  __shared__ float          vw_s[512];                                  // v_W, SWZ'd g
  __shared__ float          pw_s[16];                                   // [wave][b]

  for (int x = tid; x < 4 * 260; x += NTHR) hf[x] = 0.0f;
  for (int x = tid; x < 4 * 264; x += NTHR) hb[x] = 0;
  { const int o = tid >> 8, g = tid & 255; vw_s[o * 256 + SWZ(g)] = v_W[tid]; }
  __syncthreads();

  const int eg8 = tid & 7, ebb = (tid >> 3) & 1, ell = (tid >> 4) & 1, jsl = tid >> 5;

#pragma unroll 1
  for (int i = 0; i < TT; ++i) {
    float2 xv[BW];
#pragma unroll
    for (int b = 0; b < BW; b++) xv[b] = ((const float2*)received)[(size_t)(b0 + b) * TT + i];

    // ===== G1: gh0 = h0 @ Whh0^T -> layer-0 gates -> hn0 (rows 0,1) =====
    {
      bfrag a0[8];
#pragma unroll
      for (int c = 0; c < 8; c++)
        a0[c] = (col < BW) ? *(const bfrag*)&hb[col * 264 + c * 32 + q * 8] : zero_frag();
#pragma unroll
      for (int r2 = 0; r2 < 2; r2++) {
        const int nt16 = wave + 8 * r2;
        bfrag bb[24];
#pragma unroll
        for (int c = 0; c < 8; c++) {
          bb[c]      = W1[((nt16 * 3 + 0) * 8 + c) * 64 + lane];
          bb[8 + c]  = W1[((nt16 * 3 + 1) * 8 + c) * 64 + lane];
          bb[16 + c] = W1[((nt16 * 3 + 2) * 8 + c) * 64 + lane];
        }
        f4 aR = {0, 0, 0, 0}, aZ = {0, 0, 0, 0}, aN = {0, 0, 0, 0};
#pragma unroll
        for (int c = 0; c < 8; c++) {
          aR = mfma16(a0[c], bb[c], aR);
          aZ = mfma16(a0[c], bb[8 + c], aZ);
          aN = mfma16(a0[c], bb[16 + c], aN);
        }
        if (lane < 16) {
          const int nm = nt16 * 16 + col;
#pragma unroll
          for (int reg = 0; reg < BW; reg++) {
            const int b = reg;
            const float rr = sigf(xv[b].x * wxr0v[r2] + xv[b].y * wxr1v[r2] + br0v[r2] + aR[reg]);
            const float zz = sigf(xv[b].x * wxz0v[r2] + xv[b].y * wxz1v[r2] + bz0v[r2] + aZ[reg]);
            const float nn = tanh_fast(xv[b].x * wxn0v[r2] + xv[b].y * wxn1v[r2] + bni0v[r2] +
                                       rr * (aN[reg] + bnh0v[r2]));
            const float hn0 = (1.0f - zz) * nn + zz * hf[b * 260 + nm];
            hnb[b * 264 + nm] = f2bf(hn0);
            bufL[((i * 2 + 0) * 2 + b) * 264 + nm] = f2fp8(hn0);
          }
        }
      }
    }
    __syncthreads();

    // ===== G2: gi1 + gh1 -> layer-1 gates -> hn1 (rows 2,3) + out_W partial =====
    {
      bfrag ai[8], ah[8];
#pragma unroll
      for (int c = 0; c < 8; c++) {
        ai[c] = (col < BW) ? *(const bfrag*)&hnb[col * 264 + c * 32 + q * 8] : zero_frag();
        ah[c] = (col < BW) ? *(const bfrag*)&hb[(2 + col) * 264 + c * 32 + q * 8] : zero_frag();
      }
      float pv[BW] = {0.f, 0.f};
#pragma unroll
      for (int r2 = 0; r2 < 2; r2++) {
        const int nt16 = wave + 8 * r2;
        bfrag bb[24];
#pragma unroll
        for (int c = 0; c < 8; c++) {
          bb[c]      = W2I[((nt16 * 3 + 0) * 8 + c) * 64 + lane];
          bb[8 + c]  = W2I[((nt16 * 3 + 1) * 8 + c) * 64 + lane];
          bb[16 + c] = W2I[((nt16 * 3 + 2) * 8 + c) * 64 + lane];
        }
        f4 iR = {0, 0, 0, 0}, iZ = {0, 0, 0, 0}, iN = {0, 0, 0, 0};
#pragma unroll
        for (int c = 0; c < 8; c++) {
          iR = mfma16(ai[c], bb[c], iR);
          iZ = mfma16(ai[c], bb[8 + c], iZ);
          iN = mfma16(ai[c], bb[16 + c], iN);
        }
#pragma unroll
        for (int c = 0; c < 8; c++) {
          bb[c]      = W2H[((nt16 * 3 + 0) * 8 + c) * 64 + lane];
          bb[8 + c]  = W2H[((nt16 * 3 + 1) * 8 + c) * 64 + lane];
          bb[16 + c] = W2H[((nt16 * 3 + 2) * 8 + c) * 64 + lane];
        }
        f4 hR = {0, 0, 0, 0}, hZ = {0, 0, 0, 0}, hN = {0, 0, 0, 0};
#pragma unroll
        for (int c = 0; c < 8; c++) {
          hR = mfma16(ah[c], bb[c], hR);
          hZ = mfma16(ah[c], bb[8 + c], hZ);
          hN = mfma16(ah[c], bb[16 + c], hN);
        }
        if (lane < 16) {
          const int nm = nt16 * 16 + col;
#pragma unroll
          for (int reg = 0; reg < BW; reg++) {
            const int b = reg;
            const float rr = sigf(iR[reg] + hR[reg] + br1v[r2]);
            const float zz = sigf(iZ[reg] + hZ[reg] + bz1v[r2]);
            const float nn = tanh_fast(iN[reg] + bni1v[r2] + rr * (hN[reg] + bnh1v[r2]));
            const float hn1 = (1.0f - zz) * nn + zz * hf[(2 + b) * 260 + nm];
            hnb[(2 + b) * 264 + nm] = f2bf(hn1);
            bufL[((i * 2 + 1) * 2 + b) * 264 + nm] = f2fp8(hn1);
            pv[reg] += hn1 * owvv[r2];
          }
        }
      }
#pragma unroll
      for (int reg = 0; reg < BW; reg++) {
#pragma unroll
        for (int d = 1; d < 16; d <<= 1) pv[reg] += __shfl_xor(pv[reg], d, 64);
      }
      if (lane == 0) {
#pragma unroll
        for (int reg = 0; reg < BW; reg++) pw_s[wave * 2 + reg] = pv[reg];
      }
    }
    __syncthreads();

    // ===== G3: hn @ [attnW_s | attnW_h]^T -> es_s (fp32, SWZ) / ehL (fp8); pp fold =====
    {
      bfrag a3[8];
#pragma unroll
      for (int c = 0; c < 8; c++)
        a3[c] = (col < 4) ? *(const bfrag*)&hnb[col * 264 + c * 32 + q * 8] : zero_frag();
#pragma unroll
      for (int tt = 0; tt < 4; tt++) {
        const int t = wave * 4 + tt;
        bfrag bb[8];
#pragma unroll
        for (int c = 0; c < 8; c++) bb[c] = B3[(t * 8 + c) * 64 + lane];
        f4 acc = {0, 0, 0, 0};
#pragma unroll
        for (int c = 0; c < 8; c++) acc = mfma16(a3[c], bb[c], acc);
        if (lane < 16) {                      // rows m=reg = l*2+b
          const int n = t * 16 + col;
#pragma unroll
          for (int reg = 0; reg < 4; reg++) {
            const int l = reg >> 1, b = reg & 1;
            if (t < 16) es_s[(b * 2 + l) * 264 + SWZ(n)] = acc[reg];
            else ehL[((i * 2 + l) * 2 + b) * 272 + (n - 256)] = f2fp8(acc[reg]);
          }
        }
      }
      if (tid < BW) {
        float ss = 0.0f;
#pragma unroll
        for (int w = 0; w < 8; w++) ss += pw_s[w * 2 + tid];
        pp[(size_t)(b0 + tid) * TT + i] = ss;
      }
    }
    __syncthreads();

    // ===== energy (all-LDS, SWZ'd es/vw -> conflict-free, no register arrays) =====
    {
      const int eb = (ebb * 2 + ell) * 264;
      for (int j = jsl; j <= i; j += 16) {
        const unsigned char* rp = &ehL[((j * 2 + ell) * 2 + ebb) * 272 + eg8 * 32];
        const uint4 d0 = *(const uint4*)rp;
        const uint4 d1 = *(const uint4*)(rp + 16);
        const unsigned int w[8] = {d0.x, d0.y, d0.z, d0.w, d1.x, d1.y, d1.z, d1.w};
        float l0 = 0.0f, l1 = 0.0f;
#pragma unroll
        for (int m = 0; m < 8; m++) {
#pragma unroll
          for (int k = 0; k < 4; k++) {
            const int off = (m * 4 + k) * 8 + eg8;   // SWZ(eg8*32 + m*4+k)
            const float e = tanh_fast(es_s[eb + off] + fp8byte2f(w[m], k * 8));
            l0 = fmaf(e, vw_s[off], l0);
            l1 = fmaf(e, vw_s[256 + off], l1);
          }
        }
#pragma unroll
        for (int d = 1; d < 8; d <<= 1) { l0 += __shfl_xor(l0, d, 64); l1 += __shfl_xor(l1, d, 64); }
        if (eg8 == 0) {
          lp[((j * 2 + ebb) * 2 + ell) * 2 + 0] = __expf(l0);
          lp[((j * 2 + ebb) * 2 + ell) * 2 + 1] = __expf(l1);
        }
      }
    }
    __syncthreads();

    // ===== context: thread=(jm4,h4,b); j<i fp8 bufL, j=i exact bf16 hnb; denom folded =====
    {
      const int jm4 = tid & 3;
      const int h4  = (tid >> 2) & 63;
      const int cb  = tid >> 8;
      float c0[4] = {0.f, 0.f, 0.f, 0.f}, c1[4] = {0.f, 0.f, 0.f, 0.f};
      float ss0 = 0.0f, ss1 = 0.0f;
      for (int j = jm4; j < i; j += 4) {
#pragma unroll
        for (int l = 0; l < 2; l++) {
          const unsigned int u = *(const unsigned int*)(bufL + ((j * 2 + l) * 2 + cb) * 264 + h4 * 4);
          const float e0 = lp[((j * 2 + cb) * 2 + l) * 2 + 0];
          const float e1 = lp[((j * 2 + cb) * 2 + l) * 2 + 1];
          ss0 += e0; ss1 += e1;
#pragma unroll
          for (int k = 0; k < 4; k++) {
            const float v = fp8byte2f(u, k * 8);
            c0[k] = fmaf(e0, v, c0[k]);
            c1[k] = fmaf(e1, v, c1[k]);
          }
        }
      }
#pragma unroll
      for (int d = 1; d < 4; d <<= 1) {
        ss0 += __shfl_xor(ss0, d, 64);
        ss1 += __shfl_xor(ss1, d, 64);
#pragma unroll
        for (int k = 0; k < 4; k++) {
          c0[k] += __shfl_xor(c0[k], d, 64);
          c1[k] += __shfl_xor(c1[k], d, 64);
        }
      }
      if (jm4 == 0) {
#pragma unroll
        for (int l = 0; l < 2; l++) {     // exact j=i term (bf16 fresh hidden)
          const float e0 = lp[((i * 2 + cb) * 2 + l) * 2 + 0];
          const float e1 = lp[((i * 2 + cb) * 2 + l) * 2 + 1];
          ss0 += e0; ss1 += e1;
          const unsigned short* hp = &hnb[(l * 2 + cb) * 264 + h4 * 4];
#pragma unroll
          for (int k = 0; k < 4; k++) {
            const float v = bf2f(hp[k]);
            c0[k] = fmaf(e0, v, c0[k]);
            c1[k] = fmaf(e1, v, c1[k]);
          }
        }
        const float inv0 = rcpf(ss0), inv1 = rcpf(ss1);
#pragma unroll
        for (int k = 0; k < 4; k++) {
          cacb[(0 * 2 + cb) * 264 + h4 * 4 + k] = f2bf(c0[k] * inv0);
          cacb[(1 * 2 + cb) * 264 + h4 * 4 + k] = f2bf(c1[k] * inv1);
        }
      }
    }
    __syncthreads();

    // ===== G4: h = [cac|hn] @ fc_W^T + fc_b (K=512) -> new carry (rows o*2+b) =====
    {
      bfrag a4[16];
      if (col < 4) {
#pragma unroll
        for (int c = 0; c < 8; c++) {
          a4[c]     = *(const bfrag*)&cacb[col * 264 + c * 32 + q * 8];
          a4[c + 8] = *(const bfrag*)&hnb[col * 264 + c * 32 + q * 8];
        }
      } else {
#pragma unroll
        for (int c = 0; c < 16; c++) a4[c] = zero_frag();
      }
#pragma unroll
      for (int r2 = 0; r2 < 2; r2++) {
        const int t16 = wave + 8 * r2;
        bfrag bb[16];
#pragma unroll
        for (int c = 0; c < 16; c++) bb[c] = B4[(t16 * 16 + c) * 64 + lane];
        f4 acc = {0, 0, 0, 0};
#pragma unroll
        for (int c = 0; c < 16; c++) acc = mfma16(a4[c], bb[c], acc);
        if (lane < 16) {
          const int nm = t16 * 16 + col;
#pragma unroll
          for (int reg = 0; reg < 4; reg++) {
            const float v = acc[reg] + fcbv[r2];
            hf[reg * 260 + nm] = v;
            hb[reg * 264 + nm] = f2bf(v);
          }
        }
      }
    }
    __syncthreads();

    // ===== per-step grid drift-barrier (pure performance throttle: no cross-WG
    // data flow exists, so correctness never depends on it; all 256 WGs are
    // co-resident at 1 WG/CU so the spin cannot deadlock) =====
    if (tid == 0) {
      __hip_atomic_fetch_add(bar, 1u, __ATOMIC_RELAXED, __HIP_MEMORY_SCOPE_AGENT);
      const unsigned int target = (unsigned int)NBLK * (unsigned int)(i + 1);
      while (__hip_atomic_load(bar, __ATOMIC_RELAXED, __HIP_MEMORY_SCOPE_AGENT) < target)
        __builtin_amdgcn_s_sleep(2);
    }
    __syncthreads();
  }
}

__global__ __launch_bounds__(256) void final_combine(const float* __restrict__ ws_p,
                                                     const float* __restrict__ out_b,
                                                     float* __restrict__ out) {
  const int gidx = blockIdx.x * blockDim.x + threadIdx.x;
  if (gidx >= BATCH * TT) return;
  const int b = gidx >> 6;
  const int t = gidx & 63;
  const int idx = (t >= TT - DD - 1) ? (TT - 1) : (t + DD);
  const float* p1 = ws_p;
  const float* p2 = ws_p + (size_t)BATCH * TT;
  const float v = p1[(size_t)b * TT + t] + p2[(size_t)b * TT + idx] + out_b[0];
  out[gidx] = 1.0f / (1.0f + __expf(-v));
}

extern "C" void kernel_launch(void* const* d_in, const int* in_sizes, int n_in,
                              void* d_out, int out_size, void* d_ws, size_t ws_size,
                              hipStream_t stream) {
  const float* received = (const float*)d_in[0];
  const float* g1_Wih0 = (const float*)d_in[1];
  const float* g1_Whh0 = (const float*)d_in[2];
  const float* g1_bih0 = (const float*)d_in[3];
  const float* g1_bhh0 = (const float*)d_in[4];
  const float* g1_Wih1 = (const float*)d_in[5];
  const float* g1_Whh1 = (const float*)d_in[6];
  const float* g1_bih1 = (const float*)d_in[7];
  const float* g1_bhh1 = (const float*)d_in[8];
  const float* g2_Wih0 = (const float*)d_in[9];
  const float* g2_Whh0 = (const float*)d_in[10];
  const float* g2_bih0 = (const float*)d_in[11];
  const float* g2_bhh0 = (const float*)d_in[12];
  const float* g2_Wih1 = (const float*)d_in[13];
  const float* g2_Whh1 = (const float*)d_in[14];
  const float* g2_bih1 = (const float*)d_in[15];
  const float* g2_bhh1 = (const float*)d_in[16];
  const float* fc_W   = (const float*)d_in[17];
  const float* fc_b   = (const float*)d_in[18];
  const float* attn_W = (const float*)d_in[19];
  const float* v_W    = (const float*)d_in[20];
  const float* out_W  = (const float*)d_in[21];
  const float* out_b  = (const float*)d_in[22];

  // ws layout: bar (256 B, zeroed each launch) | fp32 pp[2*B*T] | bf16 wf[WF_TOTAL]
  unsigned int* bar = (unsigned int*)d_ws;
  float* ws_p = (float*)((char*)d_ws + 256);
  unsigned short* wf = (unsigned short*)(ws_p + 2 * BATCH * TT);

  hipMemsetAsync(d_ws, 0, 256, stream);

  hipLaunchKernelGGL(prep_weights, dim3((WF_TOTAL + 255) / 256), dim3(256), 0, stream,
                     g1_Whh0, g1_Wih1, g1_Whh1, g2_Whh0, g2_Wih1, g2_Whh1,
                     attn_W, fc_W, wf);

  hipLaunchKernelGGL(gru_attn, dim3(NBLK), dim3(NTHR), 0, stream,
                     received,
                     g1_Wih0, g1_bih0, g1_bhh0, g1_bih1, g1_bhh1,
                     g2_Wih0, g2_bih0, g2_bhh0, g2_bih1, g2_bhh1,
                     fc_b, v_W, out_W, wf, bar, ws_p);

  hipLaunchKernelGGL(final_combine, dim3((BATCH * TT + 255) / 256), dim3(256), 0, stream,
                     ws_p, out_b, (float*)d_out);
}

// Round 9
// 7377.401 us; speedup vs baseline: 1.1052x; 1.1052x over previous
//
#include <hip/hip_runtime.h>

// Problem constants
#define BATCH 256
#define TT    64
#define HH    256
#define DD    8

// Tiling: 2 stacks * 128 batch-blocks of BW=2 -> 256 WGs (1/CU), 512 thr (8 waves)
#define BW    2
#define NTHR  512
#define NBLK  (2 * (BATCH / BW))

typedef __attribute__((ext_vector_type(8))) short bfrag;   // 8 bf16 (MFMA A/B operand)
typedef __attribute__((ext_vector_type(4))) float f4;      // MFMA C/D

#define SWZ(g) ((((g) & 31) << 3) | ((g) >> 5))

__device__ __forceinline__ float rcpf(float x) { return __builtin_amdgcn_rcpf(x); }
__device__ __forceinline__ float sigf(float x) { return rcpf(1.0f + __expf(-x)); }
__device__ __forceinline__ float tanh_fast(float x) {
  const float e = __expf(-2.0f * x);
  return __builtin_fmaf(2.0f, rcpf(1.0f + e), -1.0f);
}
__device__ __forceinline__ unsigned short f2bf(float f) {
  union { float f; unsigned int u; } v; v.f = f;
  return (unsigned short)((v.u + 0x7fffu + ((v.u >> 16) & 1u)) >> 16);
}
__device__ __forceinline__ float bf2f(unsigned short u) {
  union { unsigned int u; float f; } v; v.u = ((unsigned int)u) << 16; return v.f;
}
// fp8 e4m3 via HW cvt (round-trip self-consistent; OCP on gfx950)
__device__ __forceinline__ unsigned char f2fp8(float x) {
  return (unsigned char)(__builtin_amdgcn_cvt_pk_fp8_f32(x, 0.0f, 0, false) & 0xff);
}
__device__ __forceinline__ float fp8byte2f(unsigned int w, int byteshift) {
  return __builtin_amdgcn_cvt_f32_fp8(w >> byteshift, 0);
}
__device__ __forceinline__ bfrag zero_frag() {
  bfrag r;
#pragma unroll
  for (int x = 0; x < 8; x++) r[x] = 0;
  return r;
}
__device__ __forceinline__ f4 mfma16(bfrag a, bfrag b, f4 c) {
  return __builtin_amdgcn_mfma_f32_16x16x32_bf16(a, b, c, 0, 0, 0);
}

// 8-frag GEMM block: load 8 B-frags, run 8 MFMAs. 32 VGPRs of B live at once
// (vs the old bb[24] batch = 96 VGPRs -> spills at the 128-VGPR allocation).
__device__ __forceinline__ f4 gemm8(const bfrag* __restrict__ Bbase, const bfrag a[8],
                                    int tileidx, int lane, f4 acc) {
  bfrag bb[8];
#pragma unroll
  for (int c = 0; c < 8; c++) bb[c] = Bbase[(tileidx * 8 + c) * 64 + lane];
#pragma unroll
  for (int c = 0; c < 8; c++) acc = mfma16(a[c], bb[c], acc);
  return acc;
}

// ---------- weight fragment layout (UNCHANGED from rounds 4-8) ----------
#define W1_ELEMS  196608
#define STACK_W   (3 * W1_ELEMS)
#define B3_OFF    (2 * STACK_W)
#define B4_OFF    (B3_OFF + 131072)
#define WF_TOTAL  (B4_OFF + 131072)

__global__ __launch_bounds__(256) void prep_weights(
    const float* __restrict__ g1_Whh0, const float* __restrict__ g1_Wih1, const float* __restrict__ g1_Whh1,
    const float* __restrict__ g2_Whh0, const float* __restrict__ g2_Wih1, const float* __restrict__ g2_Whh1,
    const float* __restrict__ attn_W, const float* __restrict__ fc_W,
    unsigned short* __restrict__ wf) {
  const int id = blockIdx.x * 256 + threadIdx.x;
  if (id >= WF_TOTAL) return;
  float src;
  if (id < 2 * STACK_W) {
    const int s = id / STACK_W, r = id % STACK_W;
    const int mm = r / W1_ELEMS, e = r % W1_ELEMS;
    const int j = e & 7, lane = (e >> 3) & 63, c = (e >> 9) & 7, t = e >> 12;
    const int nt = t / 3, g = t % 3;
    const int n = nt * 16 + (lane & 15);
    const int k = c * 32 + ((lane >> 4) << 3) + j;
    const float* W = (mm == 0) ? (s ? g2_Whh0 : g1_Whh0)
                   : (mm == 1) ? (s ? g2_Wih1 : g1_Wih1)
                               : (s ? g2_Whh1 : g1_Whh1);
    src = W[(g * 256 + n) * 256 + k];
  } else if (id < B4_OFF) {
    const int e = id - B3_OFF;
    const int j = e & 7, lane = (e >> 3) & 63, c = (e >> 9) & 7, t = e >> 12;
    const int n = t * 16 + (lane & 15);
    const int k = c * 32 + ((lane >> 4) << 3) + j;
    src = (n < 256) ? attn_W[n * 512 + k] : attn_W[(n - 256) * 512 + 256 + k];
  } else {
    const int e = id - B4_OFF;
    const int j = e & 7, lane = (e >> 3) & 63, c = (e >> 9) & 15, t = e >> 13;
    const int n = t * 16 + (lane & 15);
    const int k = c * 32 + ((lane >> 4) << 3) + j;
    src = fc_W[n * 512 + k];
  }
  wf[id] = f2bf(src);
}

__global__ __launch_bounds__(NTHR, 1) void gru_attn(
    const float* __restrict__ received,
    const float* __restrict__ g1_Wih0, const float* __restrict__ g1_bih0, const float* __restrict__ g1_bhh0,
    const float* __restrict__ g1_bih1, const float* __restrict__ g1_bhh1,
    const float* __restrict__ g2_Wih0, const float* __restrict__ g2_bih0, const float* __restrict__ g2_bhh0,
    const float* __restrict__ g2_bih1, const float* __restrict__ g2_bhh1,
    const float* __restrict__ fc_b, const float* __restrict__ v_W, const float* __restrict__ out_W,
    const unsigned short* __restrict__ wf,
    float* __restrict__ ws_p) {
  const int tid  = threadIdx.x;
  const int lane = tid & 63, wave = tid >> 6;   // 8 waves
  const int col  = lane & 15, q = lane >> 4;
  const int s    = blockIdx.x & 1;              // stack parity
  const int b0   = (blockIdx.x >> 1) * BW;

  const float* Wih0 = s ? g2_Wih0 : g1_Wih0;
  const float* bih0 = s ? g2_bih0 : g1_bih0;
  const float* bhh0 = s ? g2_bhh0 : g1_bhh0;
  const float* bih1 = s ? g2_bih1 : g1_bih1;
  const float* bhh1 = s ? g2_bhh1 : g1_bhh1;

  const bfrag* W1  = (const bfrag*)(wf + (size_t)s * STACK_W);
  const bfrag* W2I = W1 + W1_ELEMS / 8;
  const bfrag* W2H = W2I + W1_ELEMS / 8;
  const bfrag* B3  = (const bfrag*)(wf + B3_OFF);
  const bfrag* B4  = (const bfrag*)(wf + B4_OFF);

  float* pp = ws_p + (size_t)s * BATCH * TT;

  // Per-lane persistent constants, unit nm = (wave + 8*r2)*16 + col
  float wxr0v[2], wxr1v[2], wxz0v[2], wxz1v[2], wxn0v[2], wxn1v[2];
  float br0v[2], bz0v[2], bni0v[2], bnh0v[2];
  float br1v[2], bz1v[2], bni1v[2], bnh1v[2];
  float fcbv[2], owvv[2];
#pragma unroll
  for (int r2 = 0; r2 < 2; r2++) {
    const int nm = (wave + 8 * r2) * 16 + col;
    wxr0v[r2] = Wih0[nm * 2];         wxr1v[r2] = Wih0[nm * 2 + 1];
    wxz0v[r2] = Wih0[(256 + nm) * 2]; wxz1v[r2] = Wih0[(256 + nm) * 2 + 1];
    wxn0v[r2] = Wih0[(512 + nm) * 2]; wxn1v[r2] = Wih0[(512 + nm) * 2 + 1];
    br0v[r2]  = bih0[nm] + bhh0[nm];
    bz0v[r2]  = bih0[256 + nm] + bhh0[256 + nm];
    bni0v[r2] = bih0[512 + nm]; bnh0v[r2] = bhh0[512 + nm];
    br1v[r2]  = bih1[nm] + bhh1[nm];
    bz1v[r2]  = bih1[256 + nm] + bhh1[256 + nm];
    bni1v[r2] = bih1[512 + nm]; bnh1v[r2] = bhh1[512 + nm];
    fcbv[r2]  = fc_b[nm];
    owvv[r2]  = out_W[s * HH + nm];
  }

  // ---- LDS (~153 KB, 1 WG/CU). All history on-chip.
  __shared__ unsigned char  bufL[256 * 264];                            // hn hist fp8 [(j*2+l)*2+b][h]
  __shared__ unsigned char  ehL [256 * 272];                            // eh hist fp8 [(j*2+l)*2+b][g]
  __shared__ float          hf[4 * 260] __attribute__((aligned(16)));   // carry fp32
  __shared__ unsigned short hb[4 * 264] __attribute__((aligned(16)));   // carry bf16 (MFMA A)
  __shared__ unsigned short hnb[4 * 264] __attribute__((aligned(16)));  // fresh hidden bf16 [l*2+b]
  __shared__ float          es_s[4 * 264] __attribute__((aligned(16))); // s-projection [b*2+l][SWZ(g)]
  __shared__ unsigned short cacb[4 * 264] __attribute__((aligned(16))); // context bf16 [o*2+b]
  __shared__ float          lp[TT * 2 * 2 * 2];                         // exp(logit) [j][b][l][o]
  __shared__ float          vw_s[512];                                  // v_W, SWZ'd g
  __shared__ float          pw_s[16];                                   // [wave][b]

  for (int x = tid; x < 4 * 260; x += NTHR) hf[x] = 0.0f;
  for (int x = tid; x < 4 * 264; x += NTHR) hb[x] = 0;
  { const int o = tid >> 8, g = tid & 255; vw_s[o * 256 + SWZ(g)] = v_W[tid]; }
  __syncthreads();

  const int eg8 = tid & 7, ebb = (tid >> 3) & 1, ell = (tid >> 4) & 1, jsl = tid >> 5;

#pragma unroll 1
  for (int i = 0; i < TT; ++i) {
    float2 xv[BW];
#pragma unroll
    for (int b = 0; b < BW; b++) xv[b] = ((const float2*)received)[(size_t)(b0 + b) * TT + i];

    // ===== G1: gh0 = h0 @ Whh0^T -> layer-0 gates -> hn0 (rows 0,1) =====
    {
      bfrag a0[8];
#pragma unroll
      for (int c = 0; c < 8; c++)
        a0[c] = (col < BW) ? *(const bfrag*)&hb[col * 264 + c * 32 + q * 8] : zero_frag();
#pragma unroll
      for (int r2 = 0; r2 < 2; r2++) {
        const int nt16 = wave + 8 * r2;
        f4 aR = gemm8(W1, a0, nt16 * 3 + 0, lane, f4{0, 0, 0, 0});
        f4 aZ = gemm8(W1, a0, nt16 * 3 + 1, lane, f4{0, 0, 0, 0});
        f4 aN = gemm8(W1, a0, nt16 * 3 + 2, lane, f4{0, 0, 0, 0});
        if (lane < 16) {
          const int nm = nt16 * 16 + col;
#pragma unroll
          for (int reg = 0; reg < BW; reg++) {
            const int b = reg;
            const float rr = sigf(xv[b].x * wxr0v[r2] + xv[b].y * wxr1v[r2] + br0v[r2] + aR[reg]);
            const float zz = sigf(xv[b].x * wxz0v[r2] + xv[b].y * wxz1v[r2] + bz0v[r2] + aZ[reg]);
            const float nn = tanh_fast(xv[b].x * wxn0v[r2] + xv[b].y * wxn1v[r2] + bni0v[r2] +
                                       rr * (aN[reg] + bnh0v[r2]));
            const float hn0 = (1.0f - zz) * nn + zz * hf[b * 260 + nm];
            hnb[b * 264 + nm] = f2bf(hn0);
            bufL[((i * 2 + 0) * 2 + b) * 264 + nm] = f2fp8(hn0);
          }
        }
      }
    }
    __syncthreads();

    // ===== G2: gi1 + gh1 -> layer-1 gates -> hn1 (rows 2,3) + out_W partial =====
    {
      bfrag ai[8], ah[8];
#pragma unroll
      for (int c = 0; c < 8; c++) {
        ai[c] = (col < BW) ? *(const bfrag*)&hnb[col * 264 + c * 32 + q * 8] : zero_frag();
        ah[c] = (col < BW) ? *(const bfrag*)&hb[(2 + col) * 264 + c * 32 + q * 8] : zero_frag();
      }
      float pv[BW] = {0.f, 0.f};
#pragma unroll
      for (int r2 = 0; r2 < 2; r2++) {
        const int nt16 = wave + 8 * r2;
        f4 gR = gemm8(W2I, ai, nt16 * 3 + 0, lane, f4{0, 0, 0, 0});
        gR    = gemm8(W2H, ah, nt16 * 3 + 0, lane, gR);
        f4 gZ = gemm8(W2I, ai, nt16 * 3 + 1, lane, f4{0, 0, 0, 0});
        gZ    = gemm8(W2H, ah, nt16 * 3 + 1, lane, gZ);
        f4 gN = gemm8(W2I, ai, nt16 * 3 + 2, lane, f4{0, 0, 0, 0});
        f4 hN = gemm8(W2H, ah, nt16 * 3 + 2, lane, f4{0, 0, 0, 0});
        if (lane < 16) {
          const int nm = nt16 * 16 + col;
#pragma unroll
          for (int reg = 0; reg < BW; reg++) {
            const int b = reg;
            const float rr = sigf(gR[reg] + br1v[r2]);
            const float zz = sigf(gZ[reg] + bz1v[r2]);
            const float nn = tanh_fast(gN[reg] + bni1v[r2] + rr * (hN[reg] + bnh1v[r2]));
            const float hn1 = (1.0f - zz) * nn + zz * hf[(2 + b) * 260 + nm];
            hnb[(2 + b) * 264 + nm] = f2bf(hn1);
            bufL[((i * 2 + 1) * 2 + b) * 264 + nm] = f2fp8(hn1);
            pv[reg] += hn1 * owvv[r2];
          }
        }
      }
#pragma unroll
      for (int reg = 0; reg < BW; reg++) {
#pragma unroll
        for (int d = 1; d < 16; d <<= 1) pv[reg] += __shfl_xor(pv[reg], d, 64);
      }
      if (lane == 0) {
#pragma unroll
        for (int reg = 0; reg < BW; reg++) pw_s[wave * 2 + reg] = pv[reg];
      }
    }
    __syncthreads();

    // ===== G3: hn @ [attnW_s | attnW_h]^T -> es_s (fp32, SWZ) / ehL (fp8); pp fold =====
    {
      bfrag a3[8];
#pragma unroll
      for (int c = 0; c < 8; c++)
        a3[c] = (col < 4) ? *(const bfrag*)&hnb[col * 264 + c * 32 + q * 8] : zero_frag();
#pragma unroll
      for (int tt = 0; tt < 4; tt++) {
        const int t = wave * 4 + tt;
        f4 acc = gemm8(B3, a3, t, lane, f4{0, 0, 0, 0});
        if (lane < 16) {                      // rows m=reg = l*2+b
          const int n = t * 16 + col;
#pragma unroll
          for (int reg = 0; reg < 4; reg++) {
            const int l = reg >> 1, b = reg & 1;
            if (t < 16) es_s[(b * 2 + l) * 264 + SWZ(n)] = acc[reg];
            else ehL[((i * 2 + l) * 2 + b) * 272 + (n - 256)] = f2fp8(acc[reg]);
          }
        }
      }
      if (tid < BW) {
        float ss = 0.0f;
#pragma unroll
        for (int w = 0; w < 8; w++) ss += pw_s[w * 2 + tid];
        pp[(size_t)(b0 + tid) * TT + i] = ss;
      }
    }
    __syncthreads();

    // ===== energy (all-LDS, SWZ'd es/vw -> conflict-free) =====
    {
      const int eb = (ebb * 2 + ell) * 264;
      for (int j = jsl; j <= i; j += 16) {
        const unsigned char* rp = &ehL[((j * 2 + ell) * 2 + ebb) * 272 + eg8 * 32];
        const uint4 d0 = *(const uint4*)rp;
        const uint4 d1 = *(const uint4*)(rp + 16);
        const unsigned int w[8] = {d0.x, d0.y, d0.z, d0.w, d1.x, d1.y, d1.z, d1.w};
        float l0 = 0.0f, l1 = 0.0f;
#pragma unroll
        for (int m = 0; m < 8; m++) {
#pragma unroll
          for (int k = 0; k < 4; k++) {
            const int off = (m * 4 + k) * 8 + eg8;   // SWZ(eg8*32 + m*4+k)
            const float e = tanh_fast(es_s[eb + off] + fp8byte2f(w[m], k * 8));
            l0 = fmaf(e, vw_s[off], l0);
            l1 = fmaf(e, vw_s[256 + off], l1);
          }
        }
#pragma unroll
        for (int d = 1; d < 8; d <<= 1) { l0 += __shfl_xor(l0, d, 64); l1 += __shfl_xor(l1, d, 64); }
        if (eg8 == 0) {
          lp[((j * 2 + ebb) * 2 + ell) * 2 + 0] = __expf(l0);
          lp[((j * 2 + ebb) * 2 + ell) * 2 + 1] = __expf(l1);
        }
      }
    }
    __syncthreads();

    // ===== context: thread=(jm4,h4,b); j<i fp8 bufL, j=i exact bf16 hnb; denom folded =====
    {
      const int jm4 = tid & 3;
      const int h4  = (tid >> 2) & 63;
      const int cb  = tid >> 8;
      float c0[4] = {0.f, 0.f, 0.f, 0.f}, c1[4] = {0.f, 0.f, 0.f, 0.f};
      float ss0 = 0.0f, ss1 = 0.0f;
      for (int j = jm4; j < i; j += 4) {
#pragma unroll
        for (int l = 0; l < 2; l++) {
          const unsigned int u = *(const unsigned int*)(bufL + ((j * 2 + l) * 2 + cb) * 264 + h4 * 4);
          const float e0 = lp[((j * 2 + cb) * 2 + l) * 2 + 0];
          const float e1 = lp[((j * 2 + cb) * 2 + l) * 2 + 1];
          ss0 += e0; ss1 += e1;
#pragma unroll
          for (int k = 0; k < 4; k++) {
            const float v = fp8byte2f(u, k * 8);
            c0[k] = fmaf(e0, v, c0[k]);
            c1[k] = fmaf(e1, v, c1[k]);
          }
        }
      }
#pragma unroll
      for (int d = 1; d < 4; d <<= 1) {
        ss0 += __shfl_xor(ss0, d, 64);
        ss1 += __shfl_xor(ss1, d, 64);
#pragma unroll
        for (int k = 0; k < 4; k++) {
          c0[k] += __shfl_xor(c0[k], d, 64);
          c1[k] += __shfl_xor(c1[k], d, 64);
        }
      }
      if (jm4 == 0) {
#pragma unroll
        for (int l = 0; l < 2; l++) {     // exact j=i term (bf16 fresh hidden)
          const float e0 = lp[((i * 2 + cb) * 2 + l) * 2 + 0];
          const float e1 = lp[((i * 2 + cb) * 2 + l) * 2 + 1];
          ss0 += e0; ss1 += e1;
          const unsigned short* hp = &hnb[(l * 2 + cb) * 264 + h4 * 4];
#pragma unroll
          for (int k = 0; k < 4; k++) {
            const float v = bf2f(hp[k]);
            c0[k] = fmaf(e0, v, c0[k]);
            c1[k] = fmaf(e1, v, c1[k]);
          }
        }
        const float inv0 = rcpf(ss0), inv1 = rcpf(ss1);
#pragma unroll
        for (int k = 0; k < 4; k++) {
          cacb[(0 * 2 + cb) * 264 + h4 * 4 + k] = f2bf(c0[k] * inv0);
          cacb[(1 * 2 + cb) * 264 + h4 * 4 + k] = f2bf(c1[k] * inv1);
        }
      }
    }
    __syncthreads();

    // ===== G4: h = [cac|hn] @ fc_W^T + fc_b (K=512) -> new carry (rows o*2+b) =====
    {
      bfrag a4c[8], a4h[8];
      if (col < 4) {
#pragma unroll
        for (int c = 0; c < 8; c++) {
          a4c[c] = *(const bfrag*)&cacb[col * 264 + c * 32 + q * 8];
          a4h[c] = *(const bfrag*)&hnb[col * 264 + c * 32 + q * 8];
        }
      } else {
#pragma unroll
        for (int c = 0; c < 8; c++) { a4c[c] = zero_frag(); a4h[c] = zero_frag(); }
      }
#pragma unroll
      for (int r2 = 0; r2 < 2; r2++) {
        const int t16 = wave + 8 * r2;
        f4 acc = gemm8(B4, a4c, t16 * 2 + 0, lane, f4{0, 0, 0, 0});
        acc    = gemm8(B4, a4h, t16 * 2 + 1, lane, acc);
        if (lane < 16) {
          const int nm = t16 * 16 + col;
#pragma unroll
          for (int reg = 0; reg < 4; reg++) {
            const float v = acc[reg] + fcbv[r2];
            hf[reg * 260 + nm] = v;
            hb[reg * 264 + nm] = f2bf(v);
          }
        }
      }
    }
    __syncthreads();
  }
}

__global__ __launch_bounds__(256) void final_combine(const float* __restrict__ ws_p,
                                                     const float* __restrict__ out_b,
                                                     float* __restrict__ out) {
  const int gidx = blockIdx.x * blockDim.x + threadIdx.x;
  if (gidx >= BATCH * TT) return;
  const int b = gidx >> 6;
  const int t = gidx & 63;
  const int idx = (t >= TT - DD - 1) ? (TT - 1) : (t + DD);
  const float* p1 = ws_p;
  const float* p2 = ws_p + (size_t)BATCH * TT;
  const float v = p1[(size_t)b * TT + t] + p2[(size_t)b * TT + idx] + out_b[0];
  out[gidx] = 1.0f / (1.0f + __expf(-v));
}

extern "C" void kernel_launch(void* const* d_in, const int* in_sizes, int n_in,
                              void* d_out, int out_size, void* d_ws, size_t ws_size,
                              hipStream_t stream) {
  const float* received = (const float*)d_in[0];
  const float* g1_Wih0 = (const float*)d_in[1];
  const float* g1_Whh0 = (const float*)d_in[2];
  const float* g1_bih0 = (const float*)d_in[3];
  const float* g1_bhh0 = (const float*)d_in[4];
  const float* g1_Wih1 = (const float*)d_in[5];
  const float* g1_Whh1 = (const float*)d_in[6];
  const float* g1_bih1 = (const float*)d_in[7];
  const float* g1_bhh1 = (const float*)d_in[8];
  const float* g2_Wih0 = (const float*)d_in[9];
  const float* g2_Whh0 = (const float*)d_in[10];
  const float* g2_bih0 = (const float*)d_in[11];
  const float* g2_bhh0 = (const float*)d_in[12];
  const float* g2_Wih1 = (const float*)d_in[13];
  const float* g2_Whh1 = (const float*)d_in[14];
  const float* g2_bih1 = (const float*)d_in[15];
  const float* g2_bhh1 = (const float*)d_in[16];
  const float* fc_W   = (const float*)d_in[17];
  const float* fc_b   = (const float*)d_in[18];
  const float* attn_W = (const float*)d_in[19];
  const float* v_W    = (const float*)d_in[20];
  const float* out_W  = (const float*)d_in[21];
  const float* out_b  = (const float*)d_in[22];

  // ws layout: fp32 pp[2*B*T] | bf16 wf[WF_TOTAL]   (~3 MB; all history lives in LDS)
  float* ws_p = (float*)d_ws;
  unsigned short* wf = (unsigned short*)(ws_p + 2 * BATCH * TT);

  hipLaunchKernelGGL(prep_weights, dim3((WF_TOTAL + 255) / 256), dim3(256), 0, stream,
                     g1_Whh0, g1_Wih1, g1_Whh1, g2_Whh0, g2_Wih1, g2_Whh1,
                     attn_W, fc_W, wf);

  hipLaunchKernelGGL(gru_attn, dim3(NBLK), dim3(NTHR), 0, stream,
                     received,
                     g1_Wih0, g1_bih0, g1_bhh0, g1_bih1, g1_bhh1,
                     g2_Wih0, g2_bih0, g2_bhh0, g2_bih1, g2_bhh1,
                     fc_b, v_W, out_W, wf, ws_p);

  hipLaunchKernelGGL(final_combine, dim3((BATCH * TT + 255) / 256), dim3(256), 0, stream,
                     ws_p, out_b, (float*)d_out);
}